// Round 7
// baseline (547.792 us; speedup 1.0000x reference)
//
#include <hip/hip_runtime.h>
#include <math.h>

// Problem constants (fixed by reference)
#define B_SZ 1024
#define CTXL 10
#define DIM  300
#define VOC  50000
#define KP   320      // K padded to multiple of 64 (pooled is zero-padded 300..319)
#define NTIL 391      // ceil(50000/128)
#define NSG  50       // supergroups of 8 panels -> grid = 50*64 = 3200 blocks
#define WROW 1200     // W_cls row bytes (300 fp32), 16B-aligned (75 chunks)
#define WMAXOFF 59999984  // 49999*1200 + 74*16 : last valid 16B chunk of W_cls

typedef short s16x8 __attribute__((ext_vector_type(8)));
typedef float f32x4 __attribute__((ext_vector_type(4)));

// K0: WT[v][d] = W_proj[d][v]  (into d_out used as 60MB scratch; gemm overwrites later)
__global__ void transpose_kernel(const float* __restrict__ W, float* __restrict__ WT) {
  __shared__ float tile[32][33];
  const int v0 = blockIdx.x * 32, d0 = blockIdx.y * 32;
  const int tx = threadIdx.x & 31, ty = threadIdx.x >> 5;   // 256 threads: ty=0..7
#pragma unroll
  for (int i = 0; i < 32; i += 8) {
    const int d = d0 + ty + i, v = v0 + tx;
    tile[ty + i][tx] = (d < DIM && v < VOC) ? W[d * VOC + v] : 0.f;
  }
  __syncthreads();
#pragma unroll
  for (int i = 0; i < 32; i += 8) {
    const int v = v0 + ty + i, d = d0 + tx;
    if (v < VOC && d < DIM) WT[v * DIM + d] = tile[tx][ty + i];
  }
}

// K1: pooled[b][d] = 0.1 * sum_c (ctx!=pad) * WT[id][d], bf16, zero-padded to KP
__global__ void pool_kernel(const int* __restrict__ ctx, const float* __restrict__ WT,
                            const int* __restrict__ padp, __bf16* __restrict__ pooled) {
  const int b = blockIdx.x;
  const int d = threadIdx.x;            // 0..319
  const int pad = *padp;
  float s = 0.f;
  if (d < DIM) {
#pragma unroll
    for (int c = 0; c < CTXL; ++c) {
      const int id = ctx[b * CTXL + c];
      if (id != pad) s += WT[id * DIM + d];   // coalesced 1200B row
    }
  }
  pooled[b * KP + d] = (__bf16)(s * 0.1f);
}

// K2: out = pooled @ W_cls^T + bias.
// Zero LDS, zero barriers: fully-unrolled K (10 x k32 steps), A and B fragments
// loaded global->reg in exact MFMA layout (A bf16 direct; B fp32 cvt in regs).
// A (640KB) is L2-hot for every block; B panel shared by 8 m-blocks on one XCD.
// Reads past a W_cls row end (k>=300) hit the next row (finite garbage) and are
// annihilated by A's zero K-padding; buffer end clamped to WMAXOFF.
__global__ __launch_bounds__(256, 2) void gemm_kernel(const __bf16* __restrict__ A,
                                                      const float* __restrict__ Wcls,
                                                      const float* __restrict__ bias,
                                                      float* __restrict__ out) {
  const int bid = blockIdx.x;
  // XCD grouping: panel nt's 8 m-blocks have bids {G*64 + j*8 + s} == s (mod 8)
  const int s = bid & 7;
  const int mj = (bid >> 3) & 7;
  const int G = bid >> 6;
  const int nt = G * 8 + s;
  if (nt >= NTIL) return;
  const int m0 = mj * 128;
  const int n0 = nt * 128;
  const int t = threadIdx.x;
  const int lane = t & 63;
  const int wave = t >> 6;
  const int wm = wave >> 1, wn = wave & 1;   // 2x2 waves, 64x64 output each
  const int fr = lane & 15;                  // A-row / B-col within 16
  const int hi = lane >> 4;                  // k-chunk 0..3

  f32x4 acc[4][4];
#pragma unroll
  for (int i = 0; i < 4; ++i)
#pragma unroll
    for (int j = 0; j < 4; ++j) acc[i][j] = (f32x4){0.f, 0.f, 0.f, 0.f};

  const char* Ab = (const char*)A;
  const char* Wb = (const char*)Wcls;

  int aoff[4];
#pragma unroll
  for (int mf = 0; mf < 4; ++mf)
    aoff[mf] = (m0 + wm * 64 + mf * 16 + fr) * (KP * 2);
  int boff[4];
#pragma unroll
  for (int nf = 0; nf < 4; ++nf) {
    int r = n0 + wn * 64 + nf * 16 + fr;
    if (r > VOC - 1) r = VOC - 1;            // tail rows: finite garbage, masked in epilogue
    boff[nf] = r * WROW;
  }

#pragma unroll
  for (int ks = 0; ks < 10; ++ks) {
    const int koff = ks * 32 + hi * 8;       // element offset in K for this lane
    s16x8 af[4];
#pragma unroll
    for (int mf = 0; mf < 4; ++mf)
      af[mf] = *(const s16x8*)(Ab + aoff[mf] + koff * 2);
    s16x8 bf[4];
#pragma unroll
    for (int nf = 0; nf < 4; ++nf) {
      int o0 = boff[nf] + koff * 4;
      int o1 = o0 + 16;
      if (o0 > WMAXOFF) o0 = WMAXOFF;        // only fires for k>=300 region at buffer end
      if (o1 > WMAXOFF) o1 = WMAXOFF;
      const f32x4 x0 = *(const f32x4*)(Wb + o0);
      const f32x4 x1 = *(const f32x4*)(Wb + o1);
      union { __bf16 h; short v; } cv;
      s16x8 bb;
      cv.h = (__bf16)x0[0]; bb[0] = cv.v;
      cv.h = (__bf16)x0[1]; bb[1] = cv.v;
      cv.h = (__bf16)x0[2]; bb[2] = cv.v;
      cv.h = (__bf16)x0[3]; bb[3] = cv.v;
      cv.h = (__bf16)x1[0]; bb[4] = cv.v;
      cv.h = (__bf16)x1[1]; bb[5] = cv.v;
      cv.h = (__bf16)x1[2]; bb[6] = cv.v;
      cv.h = (__bf16)x1[3]; bb[7] = cv.v;
      bf[nf] = bb;
    }
#pragma unroll
    for (int mf = 0; mf < 4; ++mf)
#pragma unroll
      for (int nf = 0; nf < 4; ++nf)
        acc[mf][nf] = __builtin_amdgcn_mfma_f32_16x16x32_bf16(af[mf], bf[nf], acc[mf][nf], 0, 0, 0);
  }

  // Epilogue: bias + store. C/D layout (m89): col = lane&15, row = (lane>>4)*4 + reg
#pragma unroll
  for (int nf = 0; nf < 4; ++nf) {
    const int col = n0 + wn * 64 + nf * 16 + fr;
    if (col < VOC) {
      const float bia = bias[col];
#pragma unroll
      for (int mf = 0; mf < 4; ++mf)
#pragma unroll
        for (int reg = 0; reg < 4; ++reg) {
          const int row = m0 + wm * 64 + mf * 16 + hi * 4 + reg;
          out[row * VOC + col] = acc[mf][nf][reg] + bia;
        }
    }
  }
}

// K3: log-softmax fix, one block per row, no LDS stash (pass-2 re-read hits L2/L3).
// 1024 threads, ~0 LDS -> 2 blocks/CU = 100% occupancy.
__global__ __launch_bounds__(1024) void softfix_kernel(float* __restrict__ out) {
  __shared__ float red[16];
  const int b = blockIdx.x;
  const int tid = threadIdx.x;
  float4* rowp = (float4*)(out + b * VOC);        // 12500 float4

  float s = 0.f;
  for (int i = tid; i < VOC / 4; i += 1024) {
    const float4 v = rowp[i];
    s += __expf(v.x) + __expf(v.y) + __expf(v.z) + __expf(v.w);
  }
#pragma unroll
  for (int off = 1; off < 64; off <<= 1) s += __shfl_xor(s, off, 64);
  if ((tid & 63) == 0) red[tid >> 6] = s;
  __syncthreads();
  float tot = 0.f;
#pragma unroll
  for (int j = 0; j < 16; ++j) tot += red[j];
  const float l = logf(tot);

  for (int i = tid; i < VOC / 4; i += 1024) {
    float4 v = rowp[i];                            // L2/L3-hot re-read
    v.x -= l; v.y -= l; v.z -= l; v.w -= l;
    rowp[i] = v;
  }
}

extern "C" void kernel_launch(void* const* d_in, const int* in_sizes, int n_in,
                              void* d_out, int out_size, void* d_ws, size_t ws_size,
                              hipStream_t stream) {
  (void)in_sizes; (void)out_size;
  if (n_in < 5) return;             // harness surprise -> fail cleanly
  const int*   ctx   = (const int*)d_in[0];
  const float* Wproj = (const float*)d_in[1];
  const float* Wcls  = (const float*)d_in[2];
  const float* bcls  = (const float*)d_in[3];
  const int*   padp  = (const int*)d_in[4];
  float* out = (float*)d_out;

  // Workspace: pooled 1024*320*2 = 655,360 B
  if (ws_size < 655360) return;   // fail cleanly instead of crashing the container
  __bf16* pooled = (__bf16*)d_ws;
  float*  WT     = out;           // 60MB transpose scratch inside d_out (gemm overwrites later)

  transpose_kernel<<<dim3(1563, 10), 256, 0, stream>>>(Wproj, WT);
  pool_kernel<<<B_SZ, KP, 0, stream>>>(ctx, WT, padp, pooled);
  gemm_kernel<<<NSG * 64, 256, 0, stream>>>(pooled, Wcls, bcls, out);
  softfix_kernel<<<B_SZ, 1024, 0, stream>>>(out);
}

// Round 8
// 501.997 us; speedup vs baseline: 1.0912x; 1.0912x over previous
//
#include <hip/hip_runtime.h>
#include <math.h>

// Problem constants (fixed by reference)
#define B_SZ 1024
#define CTXL 10
#define DIM  300
#define VOC  50000
#define NTIL 391      // ceil(50000/128)
#define NSG  50       // supergroups of 8 panels -> grid = 50*64 = 3200 blocks
#define WROW 1200     // W_cls row bytes (300 fp32)
// Packed operand layout: per (tile, ks) block: 128 rows x 32 k bf16 = 8192 B,
// row-major with 64 B per row. Fragment load = 16 rows x 64 B = 1 KB contiguous.
#define BPACK_BYTES 32030720   // 391*10 blocks * 8192
#define APACK_BYTES 655360     // 8*10 blocks * 8192
#define WS_NEED     (BPACK_BYTES + APACK_BYTES)   // 32,686,080 (proven available, round 0)

typedef short s16x8 __attribute__((ext_vector_type(8)));
typedef short s16x4 __attribute__((ext_vector_type(4)));
typedef float f32x4 __attribute__((ext_vector_type(4)));

// K0: WT[v][d] = W_proj[d][v]  (into d_out used as 60MB scratch; gemm overwrites later)
__global__ void transpose_kernel(const float* __restrict__ W, float* __restrict__ WT) {
  __shared__ float tile[32][33];
  const int v0 = blockIdx.x * 32, d0 = blockIdx.y * 32;
  const int tx = threadIdx.x & 31, ty = threadIdx.x >> 5;   // 256 threads: ty=0..7
#pragma unroll
  for (int i = 0; i < 32; i += 8) {
    const int d = d0 + ty + i, v = v0 + tx;
    tile[ty + i][tx] = (d < DIM && v < VOC) ? W[d * VOC + v] : 0.f;
  }
  __syncthreads();
#pragma unroll
  for (int i = 0; i < 32; i += 8) {
    const int v = v0 + ty + i, d = d0 + tx;
    if (v < VOC && d < DIM) WT[v * DIM + d] = tile[tx][ty + i];
  }
}

// K1: pooled[b][d] = 0.1 * sum_c (ctx!=pad) * WT[id][d], written DIRECTLY in
// A-packed fragment layout: apack[(mt*10+ks)*8192 + row*64 + (d&31)*2]
__global__ void pool_kernel(const int* __restrict__ ctx, const float* __restrict__ WT,
                            const int* __restrict__ padp, char* __restrict__ apack) {
  const int b = blockIdx.x;
  const int d = threadIdx.x;            // 0..319
  const int pad = *padp;
  float s = 0.f;
  if (d < DIM) {
#pragma unroll
    for (int c = 0; c < CTXL; ++c) {
      const int id = ctx[b * CTXL + c];
      if (id != pad) s += WT[id * DIM + d];   // coalesced 1200B row
    }
  }
  union { __bf16 h; short v; } cv;
  cv.h = (__bf16)(s * 0.1f);              // d>=300 stays exactly 0 (K padding)
  *(short*)(apack + ((b >> 7) * 10 + (d >> 5)) * 8192 + (b & 127) * 64 + (d & 31) * 2) = cv.v;
}

// K2: B-pack: W_cls fp32 [50000][300] -> bf16 fragment-major
// bpack[(nt*10+ks)*8192 + col*64 + kq*2], zero-padded in V (cols>=50000) and K (>=300).
// grid (391, 4): block packs 32 cols; thread (cl=t>>3, o=t&7) covers k o*4..o*4+4 per ks.
__global__ void bpack_kernel(const float* __restrict__ Wcls, char* __restrict__ bpack) {
  const int nt = blockIdx.x;
  const int cl = (int)(threadIdx.x >> 3);        // 0..31
  const int o  = (int)(threadIdx.x & 7);         // 0..7
  const int colg = blockIdx.y * 32 + cl;         // col within 128-tile
  const int v = nt * 128 + colg;                 // global vocab row
#pragma unroll
  for (int ks = 0; ks < 10; ++ks) {
    f32x4 x = (f32x4){0.f, 0.f, 0.f, 0.f};
    if (v < VOC && (ks < 9 || o < 3))            // k = ks*32+o*4; valid iff k+4 <= 300
      x = *(const f32x4*)((const char*)Wcls + v * WROW + ks * 128 + o * 16);
    union { __bf16 h; short s; } cv;
    s16x4 b4;
    cv.h = (__bf16)x[0]; b4[0] = cv.s;
    cv.h = (__bf16)x[1]; b4[1] = cv.s;
    cv.h = (__bf16)x[2]; b4[2] = cv.s;
    cv.h = (__bf16)x[3]; b4[3] = cv.s;
    *(s16x4*)(bpack + (nt * 10 + ks) * 8192 + colg * 64 + o * 8) = b4;
  }
}

// K3: out = pooled @ W_cls^T + bias, from packed operands.
// Zero LDS, zero barriers, zero cvt: per k32-step, 8 perfectly-coalesced 1KB
// fragment loads (16B/lane) + 16 MFMA. No clamps (operands pre-padded).
__global__ __launch_bounds__(256, 3) void gemm_kernel(const char* __restrict__ apack,
                                                      const char* __restrict__ bpack,
                                                      const float* __restrict__ bias,
                                                      float* __restrict__ out) {
  const int bid = blockIdx.x;
  // XCD grouping: panel nt's 8 m-blocks have bids {G*64 + j*8 + s} == s (mod 8)
  const int s = bid & 7;
  const int mj = (bid >> 3) & 7;
  const int G = bid >> 6;
  const int nt = G * 8 + s;
  if (nt >= NTIL) return;
  const int m0 = mj * 128;
  const int n0 = nt * 128;
  const int lane = (int)(threadIdx.x & 63);
  const int wave = (int)(threadIdx.x >> 6);
  const int wm = wave >> 1, wn = wave & 1;   // 2x2 waves, 64x64 output each
  const int fr = lane & 15;                  // row/col within fragment
  const int hi = lane >> 4;                  // k-chunk 0..3

  f32x4 acc[4][4];
#pragma unroll
  for (int i = 0; i < 4; ++i)
#pragma unroll
    for (int j = 0; j < 4; ++j) acc[i][j] = (f32x4){0.f, 0.f, 0.f, 0.f};

  int aoff[4], boff[4];
#pragma unroll
  for (int f = 0; f < 4; ++f) {
    aoff[f] = (wm * 64 + f * 16 + fr) * 64 + hi * 16;
    boff[f] = (wn * 64 + f * 16 + fr) * 64 + hi * 16;
  }
  const char* Ab = apack + mj * (10 * 8192);
  const char* Bb = bpack + nt * (10 * 8192);

#pragma unroll
  for (int ks = 0; ks < 10; ++ks) {
    const char* Ablk = Ab + ks * 8192;
    const char* Bblk = Bb + ks * 8192;
    s16x8 af[4], bf[4];
#pragma unroll
    for (int mf = 0; mf < 4; ++mf) af[mf] = *(const s16x8*)(Ablk + aoff[mf]);
#pragma unroll
    for (int nf = 0; nf < 4; ++nf) bf[nf] = *(const s16x8*)(Bblk + boff[nf]);
#pragma unroll
    for (int mf = 0; mf < 4; ++mf)
#pragma unroll
      for (int nf = 0; nf < 4; ++nf)
        acc[mf][nf] = __builtin_amdgcn_mfma_f32_16x16x32_bf16(af[mf], bf[nf], acc[mf][nf], 0, 0, 0);
  }

  // Epilogue: bias + store. C/D layout (m89): col = lane&15, row = (lane>>4)*4 + reg
#pragma unroll
  for (int nf = 0; nf < 4; ++nf) {
    const int col = n0 + wn * 64 + nf * 16 + fr;
    if (col < VOC) {
      const float bia = bias[col];
#pragma unroll
      for (int mf = 0; mf < 4; ++mf)
#pragma unroll
        for (int reg = 0; reg < 4; ++reg) {
          const int row = m0 + wm * 64 + mf * 16 + hi * 4 + reg;
          out[row * VOC + col] = acc[mf][nf][reg] + bia;
        }
    }
  }
}

// K4: log-softmax fix, one block per row (pass-2 re-read hits L2/L3).
__global__ __launch_bounds__(1024) void softfix_kernel(float* __restrict__ out) {
  __shared__ float red[16];
  const int b = blockIdx.x;
  const int tid = threadIdx.x;
  float4* rowp = (float4*)(out + b * VOC);        // 12500 float4

  float s = 0.f;
  for (int i = tid; i < VOC / 4; i += 1024) {
    const float4 v = rowp[i];
    s += __expf(v.x) + __expf(v.y) + __expf(v.z) + __expf(v.w);
  }
#pragma unroll
  for (int off = 1; off < 64; off <<= 1) s += __shfl_xor(s, off, 64);
  if ((tid & 63) == 0) red[tid >> 6] = s;
  __syncthreads();
  float tot = 0.f;
#pragma unroll
  for (int j = 0; j < 16; ++j) tot += red[j];
  const float l = logf(tot);

  for (int i = tid; i < VOC / 4; i += 1024) {
    float4 v = rowp[i];                            // L2/L3-hot re-read
    v.x -= l; v.y -= l; v.z -= l; v.w -= l;
    rowp[i] = v;
  }
}

extern "C" void kernel_launch(void* const* d_in, const int* in_sizes, int n_in,
                              void* d_out, int out_size, void* d_ws, size_t ws_size,
                              hipStream_t stream) {
  (void)in_sizes; (void)out_size;
  if (n_in < 5) return;             // harness surprise -> fail cleanly
  const int*   ctx   = (const int*)d_in[0];
  const float* Wproj = (const float*)d_in[1];
  const float* Wcls  = (const float*)d_in[2];
  const float* bcls  = (const float*)d_in[3];
  const int*   padp  = (const int*)d_in[4];
  float* out = (float*)d_out;

  if (ws_size < WS_NEED) return;    // fail cleanly; teaches us ws_size if it trips
  char* bpack = (char*)d_ws;                       // 32,030,720 B
  char* apack = (char*)d_ws + BPACK_BYTES;         //    655,360 B
  float* WT   = out;                // 60MB transpose scratch inside d_out (gemm overwrites later)

  bpack_kernel<<<dim3(NTIL, 4), 256, 0, stream>>>(Wcls, bpack);
  transpose_kernel<<<dim3(1563, 10), 256, 0, stream>>>(Wproj, WT);
  pool_kernel<<<B_SZ, 320, 0, stream>>>(ctx, WT, padp, apack);
  gemm_kernel<<<NSG * 64, 256, 0, stream>>>(apack, bpack, bcls, out);
  softfix_kernel<<<B_SZ, 1024, 0, stream>>>(out);
}